// Round 1
// baseline (1173.127 us; speedup 1.0000x reference)
//
#include <hip/hip_runtime.h>

typedef _Float16 f16;
typedef _Float16 f16x8 __attribute__((ext_vector_type(8)));
typedef float f32x4 __attribute__((ext_vector_type(4)));

#define N_TOT   8192
#define L_STEPS 32
#define H_DIM   256
#define G4      1024
#define OUT_DIM 128
#define BN      32
#define NBLK    256
#define THREADS 512

// workspace layout (bytes):
//   Wpack : 262144 f16 = 524288 B @ 0        (W_hh in B-frag order)
//   fcpack:  32768 f16 =  65536 B @ 524288   (fc_w in B-frag order)
//   bsum  :   1024 f32 =   4096 B @ 589824   (b_ih + b_hh)
#define WPACK_OFF  0
#define FCPACK_OFF 524288
#define BSUM_OFF   589824

__global__ __launch_bounds__(256) void prep_kernel(
    const float* __restrict__ W_hh, const float* __restrict__ fc_w,
    const float* __restrict__ b_ih, const float* __restrict__ b_hh,
    f16* __restrict__ Wpack, f16* __restrict__ fcpack, float* __restrict__ bsum)
{
    int p = blockIdx.x * blockDim.x + threadIdx.x;
    if (p < 262144) {
        // Wpack[((kb*64 + T)*64 + lane)*8 + e] = W_hh[g][k]
        // g = 16*T + (lane&15), k = 32*kb + 8*(lane>>4) + e
        int e = p & 7, lane = (p >> 3) & 63, T = (p >> 9) & 63, kb = p >> 15;
        int g = 16 * T + (lane & 15);
        int k = 32 * kb + 8 * (lane >> 4) + e;
        Wpack[p] = (f16)W_hh[g * 256 + k];
    } else if (p < 262144 + 32768) {
        int p2 = p - 262144;
        // fcpack[((kb*8 + ot)*64 + lane)*8 + e] = fc_w[o][k]
        int e = p2 & 7, lane = (p2 >> 3) & 63, ot = (p2 >> 9) & 7, kb = p2 >> 12;
        int o = 16 * ot + (lane & 15);
        int k = 32 * kb + 8 * (lane >> 4) + e;
        fcpack[p2] = (f16)fc_w[o * 256 + k];
    } else if (p < 262144 + 32768 + 1024) {
        int g = p - 262144 - 32768;
        bsum[g] = b_ih[g] + b_hh[g];
    }
}

__device__ __forceinline__ float sigmoid_(float x) {
    return 1.0f / (1.0f + __expf(-x));
}
__device__ __forceinline__ float tanh_(float x) {
    float t = __expf(-2.0f * x);
    return (1.0f - t) / (1.0f + t);
}

// 256 blocks x 512 threads (8 waves). Block owns 32 batch rows through all 32 steps.
// Wave w owns gate col-tiles T = 16*q + t' for t' in {w, w+8}, q in 0..3 (i,f,g,o
// quadrants land in the same lane -> in-register c/h update), both row-tiles mt=0,1.
// fc: wave w owns out-tile ot = w (o = 16w + lane&15), both mt.
__global__ __launch_bounds__(THREADS) void lstm_kernel(
    const float* __restrict__ x, const float* __restrict__ W_ih,
    const f16* __restrict__ Wpack, const float* __restrict__ bsum,
    const f16* __restrict__ fcpack, const float* __restrict__ fc_b,
    float* __restrict__ out)
{
    __shared__ __align__(16) f16 hp[2][8192];  // h in A-frag order, double-buffered

    const int tid  = threadIdx.x;
    const int wave = tid >> 6;
    const int lane = tid & 63;
    const int l15  = lane & 15;
    const int lq   = lane >> 4;
    const int n0   = blockIdx.x * BN;

    // h(t=0) = 0
    for (int i = tid; i < 8192; i += THREADS) hp[0][i] = (f16)0.0f;
    __syncthreads();

    // per-lane x-projection constants: g = 256*q + 16*(wave + 8*ti) + l15
    float wih0[2][4], wih1[2][4], bsv[2][4];
#pragma unroll
    for (int ti = 0; ti < 2; ++ti)
#pragma unroll
        for (int q = 0; q < 4; ++q) {
            int g = 256 * q + 16 * (wave + 8 * ti) + l15;
            wih0[ti][q] = W_ih[g * 2 + 0];
            wih1[ti][q] = W_ih[g * 2 + 1];
            bsv[ti][q]  = bsum[g];
        }
    const float fcbv = fc_b[16 * wave + l15];

    float c[2][2][4];
#pragma unroll
    for (int ti = 0; ti < 2; ++ti)
#pragma unroll
        for (int mt = 0; mt < 2; ++mt)
#pragma unroll
            for (int r = 0; r < 4; ++r) c[ti][mt][r] = 0.0f;

    int buf = 0;
    for (int l = 0; l < L_STEPS; ++l) {
        // ---- accumulator init = x-projection (fp32 exact) ----
        float xv0[2][4], xv1[2][4];
#pragma unroll
        for (int mt = 0; mt < 2; ++mt)
#pragma unroll
            for (int r = 0; r < 4; ++r) {
                int n = n0 + 16 * mt + 4 * lq + r;
                const float2 xv = *(const float2*)&x[(n * L_STEPS + l) * 2];
                xv0[mt][r] = xv.x;
                xv1[mt][r] = xv.y;
            }
        f32x4 acc[2][2][4];  // [ti][mt][q]
#pragma unroll
        for (int ti = 0; ti < 2; ++ti)
#pragma unroll
            for (int mt = 0; mt < 2; ++mt)
#pragma unroll
                for (int q = 0; q < 4; ++q)
#pragma unroll
                    for (int r = 0; r < 4; ++r)
                        acc[ti][mt][q][r] = bsv[ti][q] + xv0[mt][r] * wih0[ti][q]
                                                       + xv1[mt][r] * wih1[ti][q];

        // ---- gates += h @ W_hh^T  (B-frags streamed global->VGPR from L2) ----
#pragma unroll
        for (int kb = 0; kb < 8; ++kb) {
            f16x8 a0 = *(const f16x8*)&hp[buf][((kb * 2 + 0) * 64 + lane) * 8];
            f16x8 a1 = *(const f16x8*)&hp[buf][((kb * 2 + 1) * 64 + lane) * 8];
#pragma unroll
            for (int ti = 0; ti < 2; ++ti)
#pragma unroll
                for (int q = 0; q < 4; ++q) {
                    int T = 16 * q + (wave + 8 * ti);
                    f16x8 b = *(const f16x8*)&Wpack[((kb * 64 + T) * 64 + lane) * 8];
                    acc[ti][0][q] = __builtin_amdgcn_mfma_f32_16x16x32_f16(a0, b, acc[ti][0][q], 0, 0, 0);
                    acc[ti][1][q] = __builtin_amdgcn_mfma_f32_16x16x32_f16(a1, b, acc[ti][1][q], 0, 0, 0);
                }
        }

        // ---- elementwise LSTM update (all 4 gates in-register per lane) ----
#pragma unroll
        for (int ti = 0; ti < 2; ++ti) {
            int j   = 16 * (wave + 8 * ti) + l15;
            int kbj = j >> 5, qk = (j >> 3) & 3, e = j & 7;
#pragma unroll
            for (int mt = 0; mt < 2; ++mt)
#pragma unroll
                for (int r = 0; r < 4; ++r) {
                    float gi = acc[ti][mt][0][r];
                    float gf = acc[ti][mt][1][r];
                    float gg = acc[ti][mt][2][r];
                    float go = acc[ti][mt][3][r];
                    float cn = sigmoid_(gf) * c[ti][mt][r] + sigmoid_(gi) * tanh_(gg);
                    c[ti][mt][r] = cn;
                    float hv = sigmoid_(go) * tanh_(cn);
                    int laneA = (4 * lq + r) | (qk << 4);
                    hp[buf ^ 1][((kbj * 2 + mt) * 64 + laneA) * 8 + e] = (f16)hv;
                }
        }
        __syncthreads();  // the only barrier per step

        // ---- out[:, l, :] = h_new @ fc_w^T + fc_b ----
        f32x4 facc0 = {fcbv, fcbv, fcbv, fcbv};
        f32x4 facc1 = facc0;
#pragma unroll
        for (int kb = 0; kb < 8; ++kb) {
            f16x8 a0 = *(const f16x8*)&hp[buf ^ 1][((kb * 2 + 0) * 64 + lane) * 8];
            f16x8 a1 = *(const f16x8*)&hp[buf ^ 1][((kb * 2 + 1) * 64 + lane) * 8];
            f16x8 b  = *(const f16x8*)&fcpack[((kb * 8 + wave) * 64 + lane) * 8];
            facc0 = __builtin_amdgcn_mfma_f32_16x16x32_f16(a0, b, facc0, 0, 0, 0);
            facc1 = __builtin_amdgcn_mfma_f32_16x16x32_f16(a1, b, facc1, 0, 0, 0);
        }
        const int o = 16 * wave + l15;
#pragma unroll
        for (int r = 0; r < 4; ++r) {
            int na = n0 + 4 * lq + r;
            int nb = na + 16;
            out[(na * L_STEPS + l) * OUT_DIM + o] = facc0[r];
            out[(nb * L_STEPS + l) * OUT_DIM + o] = facc1[r];
        }
        buf ^= 1;
    }
}

extern "C" void kernel_launch(void* const* d_in, const int* in_sizes, int n_in,
                              void* d_out, int out_size, void* d_ws, size_t ws_size,
                              hipStream_t stream) {
    const float* x    = (const float*)d_in[0];
    const float* W_ih = (const float*)d_in[1];
    const float* W_hh = (const float*)d_in[2];
    const float* b_ih = (const float*)d_in[3];
    const float* b_hh = (const float*)d_in[4];
    const float* fc_w = (const float*)d_in[5];
    const float* fc_b = (const float*)d_in[6];
    float* out = (float*)d_out;

    char* ws = (char*)d_ws;
    f16*   Wpack  = (f16*)(ws + WPACK_OFF);
    f16*   fcpack = (f16*)(ws + FCPACK_OFF);
    float* bsum   = (float*)(ws + BSUM_OFF);

    // pack weights into MFMA B-fragment order (every call: ws is re-poisoned)
    const int prep_elems = 262144 + 32768 + 1024;
    prep_kernel<<<(prep_elems + 255) / 256, 256, 0, stream>>>(
        W_hh, fc_w, b_ih, b_hh, Wpack, fcpack, bsum);

    lstm_kernel<<<NBLK, THREADS, 0, stream>>>(
        x, W_ih, Wpack, bsum, fcpack, fc_b, out);
}

// Round 2
// 956.976 us; speedup vs baseline: 1.2259x; 1.2259x over previous
//
#include <hip/hip_runtime.h>

typedef _Float16 f16;
typedef _Float16 f16x8 __attribute__((ext_vector_type(8)));
typedef float f32x4 __attribute__((ext_vector_type(4)));

#define N_TOT   8192
#define L_STEPS 32
#define H_DIM   256
#define G4      1024
#define OUT_DIM 128
#define BN      32
#define NBLK    256
#define THREADS 512

// workspace layout (bytes):
//   Wpack : 262144 f16 = 524288 B @ 0        (W_hh in B-frag order)
//   fcpack:  32768 f16 =  65536 B @ 524288   (fc_w in B-frag order)
//   bsum  :   1024 f32 =   4096 B @ 589824   (b_ih + b_hh)
#define WPACK_OFF  0
#define FCPACK_OFF 524288
#define BSUM_OFF   589824

__global__ __launch_bounds__(256) void prep_kernel(
    const float* __restrict__ W_hh, const float* __restrict__ fc_w,
    const float* __restrict__ b_ih, const float* __restrict__ b_hh,
    f16* __restrict__ Wpack, f16* __restrict__ fcpack, float* __restrict__ bsum)
{
    int p = blockIdx.x * blockDim.x + threadIdx.x;
    if (p < 262144) {
        // Wpack[((kb*64 + T)*64 + lane)*8 + e] = W_hh[g][k]
        // g = 16*T + (lane&15), k = 32*kb + 8*(lane>>4) + e
        int e = p & 7, lane = (p >> 3) & 63, T = (p >> 9) & 63, kb = p >> 15;
        int g = 16 * T + (lane & 15);
        int k = 32 * kb + 8 * (lane >> 4) + e;
        Wpack[p] = (f16)W_hh[g * 256 + k];
    } else if (p < 262144 + 32768) {
        int p2 = p - 262144;
        // fcpack[((kb*8 + ot)*64 + lane)*8 + e] = fc_w[o][k]
        int e = p2 & 7, lane = (p2 >> 3) & 63, ot = (p2 >> 9) & 7, kb = p2 >> 12;
        int o = 16 * ot + (lane & 15);
        int k = 32 * kb + 8 * (lane >> 4) + e;
        fcpack[p2] = (f16)fc_w[o * 256 + k];
    } else if (p < 262144 + 32768 + 1024) {
        int g = p - 262144 - 32768;
        bsum[g] = b_ih[g] + b_hh[g];
    }
}

__device__ __forceinline__ float sigmoid_(float x) {
    return 1.0f / (1.0f + __expf(-x));
}
__device__ __forceinline__ float tanh_(float x) {
    float t = __expf(-2.0f * x);
    return (1.0f - t) / (1.0f + t);
}

// 256 blocks x 512 threads (8 waves, 2 waves/SIMD, 1 block/CU).
// W_hh B-frags (256 VGPR/wave) and fc B-frags (32 VGPR/wave) are REGISTER-
// RESIDENT across all 32 steps — no per-step global weight traffic.
// Wave w owns gate col-tiles T = 16*q + t' for t' in {w, w+8}, q = 0..3
// (i,f,g,o quadrants in the same lane -> in-register c/h update).
// fc output staged through LDS so global writes are line-contiguous.
__global__ __launch_bounds__(THREADS, 2) void lstm_kernel(
    const float* __restrict__ x, const float* __restrict__ W_ih,
    const f16* __restrict__ Wpack, const float* __restrict__ bsum,
    const f16* __restrict__ fcpack, const float* __restrict__ fc_b,
    float* __restrict__ out)
{
    __shared__ __align__(16) f16 hp[2][8192];          // h in A-frag order, dbuf
    __shared__ __align__(16) float obuf[BN * OUT_DIM]; // fc out staging, 16 KB

    const int tid  = threadIdx.x;
    const int wave = tid >> 6;
    const int lane = tid & 63;
    const int l15  = lane & 15;
    const int lq   = lane >> 4;
    const int n0   = blockIdx.x * BN;

    // ---- load resident weights (once) ----
    f16x8 wreg[8][2][4];  // [kb][ti][q]
#pragma unroll
    for (int kb = 0; kb < 8; ++kb)
#pragma unroll
        for (int ti = 0; ti < 2; ++ti)
#pragma unroll
            for (int q = 0; q < 4; ++q) {
                int T = 16 * q + wave + 8 * ti;
                wreg[kb][ti][q] = *(const f16x8*)&Wpack[((kb * 64 + T) * 64 + lane) * 8];
            }
    f16x8 fcw[8];
#pragma unroll
    for (int kb = 0; kb < 8; ++kb)
        fcw[kb] = *(const f16x8*)&fcpack[((kb * 8 + wave) * 64 + lane) * 8];

    // h(t=0) = 0
    for (int i = tid; i < 8192; i += THREADS) hp[0][i] = (f16)0.0f;

    // per-lane x-projection constants: g = 256*q + 16*(wave + 8*ti) + l15
    float wih0[2][4], wih1[2][4], bsv[2][4];
#pragma unroll
    for (int ti = 0; ti < 2; ++ti)
#pragma unroll
        for (int q = 0; q < 4; ++q) {
            int g = 256 * q + 16 * (wave + 8 * ti) + l15;
            wih0[ti][q] = W_ih[g * 2 + 0];
            wih1[ti][q] = W_ih[g * 2 + 1];
            bsv[ti][q]  = bsum[g];
        }
    const float fcbv = fc_b[16 * wave + l15];

    float c[2][2][4];
#pragma unroll
    for (int ti = 0; ti < 2; ++ti)
#pragma unroll
        for (int mt = 0; mt < 2; ++mt)
#pragma unroll
            for (int r = 0; r < 4; ++r) c[ti][mt][r] = 0.0f;

    // prefetch x for l=0
    float2 xc[2][4];
#pragma unroll
    for (int mt = 0; mt < 2; ++mt)
#pragma unroll
        for (int r = 0; r < 4; ++r) {
            int n = n0 + 16 * mt + 4 * lq + r;
            xc[mt][r] = *(const float2*)&x[(n * L_STEPS + 0) * 2];
        }

    __syncthreads();

    int buf = 0;
    for (int l = 0; l < L_STEPS; ++l) {
        // ---- accumulator init = x-projection (fp32 exact) ----
        f32x4 acc[2][2][4];  // [ti][mt][q]
#pragma unroll
        for (int ti = 0; ti < 2; ++ti)
#pragma unroll
            for (int mt = 0; mt < 2; ++mt)
#pragma unroll
                for (int q = 0; q < 4; ++q)
#pragma unroll
                    for (int r = 0; r < 4; ++r)
                        acc[ti][mt][q][r] = bsv[ti][q] + xc[mt][r].x * wih0[ti][q]
                                                       + xc[mt][r].y * wih1[ti][q];

        // software-prefetch x for l+1 (hidden under MFMA phase)
        float2 xn[2][4];
        if (l + 1 < L_STEPS) {
#pragma unroll
            for (int mt = 0; mt < 2; ++mt)
#pragma unroll
                for (int r = 0; r < 4; ++r) {
                    int n = n0 + 16 * mt + 4 * lq + r;
                    xn[mt][r] = *(const float2*)&x[(n * L_STEPS + l + 1) * 2];
                }
        }

        // ---- gates += h @ W_hh^T  (B register-resident, A from LDS) ----
#pragma unroll
        for (int kb = 0; kb < 8; ++kb) {
            f16x8 a0 = *(const f16x8*)&hp[buf][((kb * 2 + 0) * 64 + lane) * 8];
            f16x8 a1 = *(const f16x8*)&hp[buf][((kb * 2 + 1) * 64 + lane) * 8];
#pragma unroll
            for (int ti = 0; ti < 2; ++ti)
#pragma unroll
                for (int q = 0; q < 4; ++q) {
                    acc[ti][0][q] = __builtin_amdgcn_mfma_f32_16x16x32_f16(a0, wreg[kb][ti][q], acc[ti][0][q], 0, 0, 0);
                    acc[ti][1][q] = __builtin_amdgcn_mfma_f32_16x16x32_f16(a1, wreg[kb][ti][q], acc[ti][1][q], 0, 0, 0);
                }
        }

        // ---- elementwise LSTM update (all 4 gates in-register per lane) ----
#pragma unroll
        for (int ti = 0; ti < 2; ++ti) {
            int j   = 16 * (wave + 8 * ti) + l15;
            int kbj = j >> 5, qk = (j >> 3) & 3, e = j & 7;
#pragma unroll
            for (int mt = 0; mt < 2; ++mt)
#pragma unroll
                for (int r = 0; r < 4; ++r) {
                    float gi = acc[ti][mt][0][r];
                    float gf = acc[ti][mt][1][r];
                    float gg = acc[ti][mt][2][r];
                    float go = acc[ti][mt][3][r];
                    float cn = sigmoid_(gf) * c[ti][mt][r] + sigmoid_(gi) * tanh_(gg);
                    c[ti][mt][r] = cn;
                    float hv = sigmoid_(go) * tanh_(cn);
                    int laneA = (4 * lq + r) | (qk << 4);
                    hp[buf ^ 1][((kbj * 2 + mt) * 64 + laneA) * 8 + e] = (f16)hv;
                }
        }
        __syncthreads();  // barrier A: h_new visible

        // ---- out[:, l, :] = h_new @ fc_w^T + fc_b (B register-resident) ----
        f32x4 facc0 = {fcbv, fcbv, fcbv, fcbv};
        f32x4 facc1 = facc0;
#pragma unroll
        for (int kb = 0; kb < 8; ++kb) {
            f16x8 a0 = *(const f16x8*)&hp[buf ^ 1][((kb * 2 + 0) * 64 + lane) * 8];
            f16x8 a1 = *(const f16x8*)&hp[buf ^ 1][((kb * 2 + 1) * 64 + lane) * 8];
            facc0 = __builtin_amdgcn_mfma_f32_16x16x32_f16(a0, fcw[kb], facc0, 0, 0, 0);
            facc1 = __builtin_amdgcn_mfma_f32_16x16x32_f16(a1, fcw[kb], facc1, 0, 0, 0);
        }
        const int o = 16 * wave + l15;
#pragma unroll
        for (int r = 0; r < 4; ++r) {
            obuf[(4 * lq + r) * OUT_DIM + o]        = facc0[r];
            obuf[(16 + 4 * lq + r) * OUT_DIM + o]   = facc1[r];
        }
        __syncthreads();  // barrier B: obuf visible

        // ---- cooperative, line-contiguous global write ----
        {
            const int row = tid >> 4;
            const int gl  = ((n0 + row) * L_STEPS + l) * OUT_DIM;
#pragma unroll
            for (int half = 0; half < 2; ++half) {
                int col = (tid & 15) * 4 + half * 64;
                f32x4 v = *(const f32x4*)&obuf[row * OUT_DIM + col];
                *(f32x4*)&out[gl + col] = v;
            }
        }

#pragma unroll
        for (int mt = 0; mt < 2; ++mt)
#pragma unroll
            for (int r = 0; r < 4; ++r) xc[mt][r] = xn[mt][r];
        buf ^= 1;
    }
}

extern "C" void kernel_launch(void* const* d_in, const int* in_sizes, int n_in,
                              void* d_out, int out_size, void* d_ws, size_t ws_size,
                              hipStream_t stream) {
    const float* x    = (const float*)d_in[0];
    const float* W_ih = (const float*)d_in[1];
    const float* W_hh = (const float*)d_in[2];
    const float* b_ih = (const float*)d_in[3];
    const float* b_hh = (const float*)d_in[4];
    const float* fc_w = (const float*)d_in[5];
    const float* fc_b = (const float*)d_in[6];
    float* out = (float*)d_out;

    char* ws = (char*)d_ws;
    f16*   Wpack  = (f16*)(ws + WPACK_OFF);
    f16*   fcpack = (f16*)(ws + FCPACK_OFF);
    float* bsum   = (float*)(ws + BSUM_OFF);

    const int prep_elems = 262144 + 32768 + 1024;
    prep_kernel<<<(prep_elems + 255) / 256, 256, 0, stream>>>(
        W_hh, fc_w, b_ih, b_hh, Wpack, fcpack, bsum);

    lstm_kernel<<<NBLK, THREADS, 0, stream>>>(
        x, W_ih, Wpack, bsum, fcpack, fc_b, out);
}